// Round 2
// baseline (359.499 us; speedup 1.0000x reference)
//
#include <hip/hip_runtime.h>
#include <stdint.h>

// PCLayer closed form: x = (t - b) @ A,  A^T = 0.01*W^T + lr*S'@W^T,
// S' = -45E + 120E^2 - 210E^3,  E = lr*W^T W  (||E||~0.009; dropped 252E^4
// term contributes <1e-7 to x). Pipeline: 6 launches, no host sync.

typedef short bf16x8 __attribute__((ext_vector_type(8)));   // 8 bf16 = 4 VGPRs
typedef float f32x4  __attribute__((ext_vector_type(4)));
typedef unsigned short u16;
typedef unsigned int uint_as1 __attribute__((address_space(1)));
typedef unsigned int uint_as3 __attribute__((address_space(3)));

__device__ __forceinline__ float bf2f(u16 u) {
  union { unsigned int i; float f; } x; x.i = ((unsigned int)u) << 16; return x.f;
}
__device__ __forceinline__ u16 f2bf(float f) {  // round-to-nearest-even
  union { float f; unsigned int i; } x; x.f = f;
  unsigned int r = x.i + 0x7fffu + ((x.i >> 16) & 1u);
  return (u16)(r >> 16);
}
__device__ __forceinline__ void gl2lds16(const void* g, void* l) {
  // async 16B/lane global->LDS; LDS dst = wave-uniform base + lane*16
  __builtin_amdgcn_global_load_lds((uint_as1*)(uintptr_t)g,
                                   (uint_as3*)(uintptr_t)l, 16, 0, 0);
}
__device__ __forceinline__ bf16x8 pack8(float4 a, float4 b) {
  bf16x8 v;
  v[0]=(short)f2bf(a.x); v[1]=(short)f2bf(a.y); v[2]=(short)f2bf(a.z); v[3]=(short)f2bf(a.w);
  v[4]=(short)f2bf(b.x); v[5]=(short)f2bf(b.y); v[6]=(short)f2bf(b.z); v[7]=(short)f2bf(b.w);
  return v;
}
__device__ __forceinline__ float4 f4comb(float4 a, float4 b, float4 c,
                                         float c0, float c1, float c2) {
  float4 o;
  o.x = c0*a.x + c1*b.x + c2*c.x; o.y = c0*a.y + c1*b.y + c2*c.y;
  o.z = c0*a.z + c1*b.z + c2*c.z; o.w = c0*a.w + c1*b.w + c2*c.w;
  return o;
}

// C[M,N] = alpha * A[M,K] @ B[N,K]^T, bf16 inputs via global_load_lds.
// TM in {64,128}: M-tile (N-tile fixed 128). MODE 0: plain fp32 store;
// MODE 1: atomicAdd (split-K over blockIdx.z into pre-zeroed Cf).
template<int MODE, int TM>
__global__ __launch_bounds__(256, 2)
void gemm_bt(const u16* __restrict__ A, const u16* __restrict__ B,
             float* __restrict__ Cf, float alpha, int K, int ldc, int kc)
{
  constexpr int FM  = TM / 32;   // A frags per wave
  constexpr int RPW = TM / 4;    // A rows staged per wave
  constexpr int NLA = TM / 64;   // gl2lds ops for A per wave
  __shared__ u16 As[TM * 32];
  __shared__ u16 Bs[128 * 32];
  const int tid = threadIdx.x, w = tid >> 6, lane = tid & 63;
  const int lm = lane & 15, quad = lane >> 4;
  const int wm = w & 1, wn = w >> 1;
  const int m0 = blockIdx.x * TM, n0 = blockIdx.y * 128;
  const long k0 = (long)blockIdx.z * kc;
  const int r = lane >> 2, q = lane & 3;
  const u16* Ag = A + (long)(m0 + w * RPW + r) * K + k0 + q * 8;
  const u16* Bg = B + (long)(n0 + w * 32 + r) * K + k0 + q * 8;
  u16* Asl = As + w * RPW * 32;
  u16* Bsl = Bs + w * 1024;

  f32x4 acc[FM][4] = {};

  for (int kk = 0; kk < kc; kk += 32) {
#pragma unroll
    for (int l = 0; l < NLA; ++l) gl2lds16(Ag + (long)l * 16 * K + kk, Asl + l * 512);
    gl2lds16(Bg + kk, Bsl);
    gl2lds16(Bg + 16 * (long)K + kk, Bsl + 512);
    __syncthreads();
    bf16x8 af[FM], bv[4];
#pragma unroll
    for (int i = 0; i < FM; ++i)
      af[i] = *(const bf16x8*)(As + (wm * (TM/2) + i * 16 + lm) * 32 + quad * 8);
#pragma unroll
    for (int j = 0; j < 4; ++j)
      bv[j] = *(const bf16x8*)(Bs + (wn * 64 + j * 16 + lm) * 32 + quad * 8);
#pragma unroll
    for (int i = 0; i < FM; ++i)
#pragma unroll
      for (int j = 0; j < 4; ++j)
        acc[i][j] = __builtin_amdgcn_mfma_f32_16x16x32_bf16(af[i], bv[j], acc[i][j], 0, 0, 0);
    __syncthreads();
  }

  // C/D layout (m89-verified): col = lane&15, row = quad*4 + reg
  const int rbase = m0 + wm * (TM/2) + quad * 4;
  const int cbase = n0 + wn * 64 + lm;
#pragma unroll
  for (int i = 0; i < FM; ++i)
#pragma unroll
    for (int j = 0; j < 4; ++j) {
      const int col = cbase + j * 16;
#pragma unroll
      for (int rr = 0; rr < 4; ++rr) {
        const long idx = (long)(rbase + i * 16 + rr) * ldc + col;
        const float v = alpha * acc[i][j][rr];
        if (MODE == 0) Cf[idx] = v;
        else           atomicAdd(&Cf[idx], v);
      }
    }
}

// 128x128-tile BT-GEMM with fp32 A (optionally S'-combine of 3 buffers in
// staging) and fp32 (BBF16=0) or bf16-via-gl2lds (BBF16=1) B.
// MODE 1: atomicAdd fp32.  MODE 2: Cb = bf16(alpha*v + addScale*Add[idx]).
template<int MODE, int BBF16, int COMB>
__global__ __launch_bounds__(256, 2)
void gemm_f32(const float* __restrict__ A0, const float* __restrict__ A1,
              const float* __restrict__ A2, float c0, float c1, float c2,
              const void* __restrict__ Bp, float* __restrict__ Cf,
              u16* __restrict__ Cb, const u16* __restrict__ Add,
              float alpha, float addScale, int K, int ldc, int kc)
{
  __shared__ u16 As[128 * 32];
  __shared__ u16 Bs[128 * 32];
  const int tid = threadIdx.x, w = tid >> 6, lane = tid & 63;
  const int lm = lane & 15, quad = lane >> 4;
  const int wm = w & 1, wn = w >> 1;
  const int m0 = blockIdx.x * 128, n0 = blockIdx.y * 128;
  const long k0 = (long)blockIdx.z * kc;
  const int r = lane >> 2, q = lane & 3;
  const long aoff = (long)(m0 + w * 32 + r) * K + k0 + q * 8;
  const long boff = (long)(n0 + w * 32 + r) * K + k0 + q * 8;
  const u16*   Bg16 = (const u16*)Bp + boff;
  const float* Bgf  = (const float*)Bp + boff;
  u16* Bsl = Bs + w * 1024;
  const int asl0 = (w * 32 + r) * 32 + q * 8;   // u16 index in As/Bs

  f32x4 acc[4][4] = {};

  for (int kk = 0; kk < kc; kk += 32) {
    float4 x0 = *(const float4*)(A0 + aoff + kk);
    float4 x1 = *(const float4*)(A0 + aoff + kk + 4);
    float4 y0 = *(const float4*)(A0 + aoff + 16 * (long)K + kk);
    float4 y1 = *(const float4*)(A0 + aoff + 16 * (long)K + kk + 4);
    if constexpr (COMB) {
      x0 = f4comb(x0, *(const float4*)(A1 + aoff + kk),
                      *(const float4*)(A2 + aoff + kk), c0, c1, c2);
      x1 = f4comb(x1, *(const float4*)(A1 + aoff + kk + 4),
                      *(const float4*)(A2 + aoff + kk + 4), c0, c1, c2);
      y0 = f4comb(y0, *(const float4*)(A1 + aoff + 16 * (long)K + kk),
                      *(const float4*)(A2 + aoff + 16 * (long)K + kk), c0, c1, c2);
      y1 = f4comb(y1, *(const float4*)(A1 + aoff + 16 * (long)K + kk + 4),
                      *(const float4*)(A2 + aoff + 16 * (long)K + kk + 4), c0, c1, c2);
    }
    if constexpr (BBF16) {
      gl2lds16(Bg16 + kk, Bsl);
      gl2lds16(Bg16 + 16 * (long)K + kk, Bsl + 512);
    } else {
      const float4 u0 = *(const float4*)(Bgf + kk);
      const float4 u1 = *(const float4*)(Bgf + kk + 4);
      const float4 v0 = *(const float4*)(Bgf + 16 * (long)K + kk);
      const float4 v1 = *(const float4*)(Bgf + 16 * (long)K + kk + 4);
      *(bf16x8*)(Bs + asl0)       = pack8(u0, u1);
      *(bf16x8*)(Bs + asl0 + 512) = pack8(v0, v1);
    }
    *(bf16x8*)(As + asl0)       = pack8(x0, x1);
    *(bf16x8*)(As + asl0 + 512) = pack8(y0, y1);
    __syncthreads();
    bf16x8 af[4], bv[4];
#pragma unroll
    for (int i = 0; i < 4; ++i) {
      af[i] = *(const bf16x8*)(As + (wm * 64 + i * 16 + lm) * 32 + quad * 8);
      bv[i] = *(const bf16x8*)(Bs + (wn * 64 + i * 16 + lm) * 32 + quad * 8);
    }
#pragma unroll
    for (int i = 0; i < 4; ++i)
#pragma unroll
      for (int j = 0; j < 4; ++j)
        acc[i][j] = __builtin_amdgcn_mfma_f32_16x16x32_bf16(af[i], bv[j], acc[i][j], 0, 0, 0);
    __syncthreads();
  }

  const int rbase = m0 + wm * 64 + quad * 4;
  const int cbase = n0 + wn * 64 + lm;
#pragma unroll
  for (int i = 0; i < 4; ++i)
#pragma unroll
    for (int j = 0; j < 4; ++j) {
      const int col = cbase + j * 16;
#pragma unroll
      for (int rr = 0; rr < 4; ++rr) {
        const long idx = (long)(rbase + i * 16 + rr) * ldc + col;
        if (MODE == 1) {
          atomicAdd(&Cf[idx], alpha * acc[i][j][rr]);
        } else {
          const float v = alpha * acc[i][j][rr] + addScale * bf2f(Add[idx]);
          Cb[idx] = f2bf(v);
        }
      }
    }
}

// One fused prep kernel: tb = bf16(t - b); Wb/WTb = bf16(W)/bf16(W)^T;
// zero Ef..P3f (contiguous 1,769,472 floats).
__global__ void conv_all(const float* __restrict__ t, const float* __restrict__ bias,
                         const float* __restrict__ W, u16* __restrict__ tb,
                         u16* __restrict__ Wb, u16* __restrict__ WTb,
                         float* __restrict__ Z)
{
  const int bx = blockIdx.x, tid = threadIdx.x;
  if (bx < 24576) {                       // t: 6,291,456 float4
    const long i4 = (long)bx * 256 + tid;
    const float4 v = ((const float4*)t)[i4];
    const float4 bb = ((const float4*)bias)[(int)(i4 % 768)];
    ushort4 o;
    o.x = f2bf(v.x - bb.x); o.y = f2bf(v.y - bb.y);
    o.z = f2bf(v.z - bb.z); o.w = f2bf(v.w - bb.w);
    ((ushort4*)tb)[i4] = o;
  } else if (bx < 24576 + 9216) {         // W: 2,359,296 scalars
    const int i = (bx - 24576) * 256 + tid;
    const float v = W[i];
    const u16 u = f2bf(v);
    Wb[i] = u;
    const int o = i / 768, c = i - o * 768;
    WTb[(long)c * 3072 + o] = u;          // 2B scatter; 4.7MB, L2-absorbed
  } else {                                // zero Ef,P2f,P3f: 442,368 float4
    const int i4 = (bx - 24576 - 9216) * 256 + tid;
    const float4 z = make_float4(0.f, 0.f, 0.f, 0.f);
    ((float4*)Z)[i4] = z;
  }
}

extern "C" void kernel_launch(void* const* d_in, const int* in_sizes, int n_in,
                              void* d_out, int out_size, void* d_ws, size_t ws_size,
                              hipStream_t stream)
{
  const float* t    = (const float*)d_in[0];   // [8,1024,3072]
  const float* W    = (const float*)d_in[1];   // [3072,768]
  const float* bias = (const float*)d_in[2];   // [3072]
  float* out = (float*)d_out;                  // [8192,768] fp32

  char* p = (char*)d_ws;                       // 71,565,312 B used
  u16*   tb  = (u16*)(p + 0);                  // 50,331,648  bf16 t-b [8192,3072]
  u16*   Wb  = (u16*)(p + 50331648);           //  4,718,592  bf16 W  [3072,768]
  u16*   WTb = (u16*)(p + 55050240);           //  4,718,592  bf16 W^T [768,3072]
  u16*   Amb = (u16*)(p + 59768832);           //  4,718,592  bf16 A^T [768,3072]
  float* Ef  = (float*)(p + 64487424);         //  2,359,296  E fp32 [768,768]
  float* P2f = (float*)(p + 66846720);         //  2,359,296  E^2 fp32
  float* P3f = (float*)(p + 69206016);         //  2,359,296  E^3 fp32

  const float lr = 0.001f;

  // 1. converts + zero (Ef,P2f,P3f contiguous after Ef)
  conv_all<<<35520, 256, 0, stream>>>(t, bias, W, tb, Wb, WTb, Ef);
  // 2. E = lr * W^T W : A=B=WTb [768,3072], split-K x8, atomic fp32
  gemm_bt<1, 128><<<dim3(6, 6, 8), 256, 0, stream>>>(WTb, WTb, Ef, lr, 3072, 768, 384);
  // 3. E^2 = E E^T (E symmetric), fp32-in, split-K x4
  gemm_f32<1, 0, 0><<<dim3(6, 6, 4), 256, 0, stream>>>(
      Ef, Ef, Ef, 1.f, 0.f, 0.f, Ef, P2f, nullptr, nullptr, 1.f, 0.f, 768, 768, 192);
  // 4. E^3 = E^2 E^T, fp32-in, split-K x4
  gemm_f32<1, 0, 0><<<dim3(6, 6, 4), 256, 0, stream>>>(
      P2f, P2f, P2f, 1.f, 0.f, 0.f, Ef, P3f, nullptr, nullptr, 1.f, 0.f, 768, 768, 192);
  // 5. A^T = lr*(S' @ W^T) + 0.01*W^T, S' combined in staging from Ef,P2f,P3f
  gemm_f32<2, 1, 1><<<dim3(6, 24, 1), 256, 0, stream>>>(
      Ef, P2f, P3f, -45.f, 120.f, -210.f, Wb, nullptr, Amb, WTb,
      lr, 0.01f, 768, 3072, 768);
  // 6. x = (t-b) @ A : TM=64 -> grid 128x6 = 768 blocks (3 blocks/CU)
  gemm_bt<0, 64><<<dim3(128, 6, 1), 256, 0, stream>>>(tb, Amb, out, 1.f, 3072, 768, 3072);
}

// Round 3
// 321.106 us; speedup vs baseline: 1.1196x; 1.1196x over previous
//
#include <hip/hip_runtime.h>
#include <stdint.h>

// PCLayer closed form, reassociated onto the big operand:
//   y = (t - b) @ W                      [8192,768]  (GEMM1, K=3072)
//   x = 0.01*y + lr * y @ S''            (GEMM2, K=768)
//   S'' = -45E + 120E^2,  E = lr*W^T W   (||E||~0.009; E^3 term < 1e-5 -> dropped)
// Small GEMMs: split-K partials (no atomics) + vectorized reduce kernels.
// 7 launches, no host sync, no memset.

typedef short bf16x8 __attribute__((ext_vector_type(8)));   // 8 bf16 = 4 VGPRs
typedef float f32x4  __attribute__((ext_vector_type(4)));
typedef unsigned short u16;
typedef unsigned int uint_as1 __attribute__((address_space(1)));
typedef unsigned int uint_as3 __attribute__((address_space(3)));

__device__ __forceinline__ float bf2f(u16 u) {
  union { unsigned int i; float f; } x; x.i = ((unsigned int)u) << 16; return x.f;
}
__device__ __forceinline__ u16 f2bf(float f) {  // round-to-nearest-even
  union { float f; unsigned int i; } x; x.f = f;
  unsigned int r = x.i + 0x7fffu + ((x.i >> 16) & 1u);
  return (u16)(r >> 16);
}
__device__ __forceinline__ void gl2lds16(const void* g, void* l) {
  // async 16B/lane global->LDS; LDS dst = wave-uniform base + lane*16
  __builtin_amdgcn_global_load_lds((uint_as1*)(uintptr_t)g,
                                   (uint_as3*)(uintptr_t)l, 16, 0, 0);
}
__device__ __forceinline__ bf16x8 pack8(float4 a, float4 b) {
  bf16x8 v;
  v[0]=(short)f2bf(a.x); v[1]=(short)f2bf(a.y); v[2]=(short)f2bf(a.z); v[3]=(short)f2bf(a.w);
  v[4]=(short)f2bf(b.x); v[5]=(short)f2bf(b.y); v[6]=(short)f2bf(b.z); v[7]=(short)f2bf(b.w);
  return v;
}
__device__ __forceinline__ float4 f4sub(float4 a, float4 b) {
  return make_float4(a.x-b.x, a.y-b.y, a.z-b.z, a.w-b.w);
}

// C[M,N(tile128)] = alpha * A[M,K] @ B[N,K]^T
// ASRC 0: A bf16 via gl2lds.  ASRC 1: A fp32 with bias-subtract, packed to bf16
//         in registers then ds_write_b128 (TM must be 64).
// EPI 0: fp32 partial store at Cf + blockIdx.z*zstride (split-K, reduced later)
// EPI 1: bf16 store Cb = bf16(alpha*acc)
// EPI 2: fp32 store Cf = alpha*acc + beta*bf2f(Yb[idx])
template<int TM, int ASRC, int EPI>
__global__ __launch_bounds__(256, 2)
void gemm(const void* __restrict__ Ap, const float* __restrict__ bias,
          const u16* __restrict__ B, float* __restrict__ Cf,
          u16* __restrict__ Cb, const u16* __restrict__ Yb,
          float alpha, float beta, int K, int ldc, int kc, long zstride)
{
  static_assert(ASRC == 0 || TM == 64, "fp32 staging only for TM=64");
  constexpr int FM  = TM / 32;   // A frags per wave
  constexpr int RPW = TM / 4;    // A rows staged per wave
  constexpr int NLA = TM / 64;   // gl2lds ops for A per wave
  __shared__ u16 As[TM * 32];
  __shared__ u16 Bs[128 * 32];
  const int tid = threadIdx.x, w = tid >> 6, lane = tid & 63;
  const int lm = lane & 15, quad = lane >> 4;
  const int wm = w & 1, wn = w >> 1;
  const int m0 = blockIdx.x * TM, n0 = blockIdx.y * 128;
  const long k0 = (long)blockIdx.z * kc;
  const int r = lane >> 2, q = lane & 3;

  const u16*   Ag  = (const u16*)Ap + (long)(m0 + w * RPW + r) * K + k0 + q * 8;
  const float* Atf = (const float*)Ap + (long)(m0 + w * RPW + r) * K + k0 + q * 8;
  const u16*   Bg  = B + (long)(n0 + w * 32 + r) * K + k0 + q * 8;
  const float4* bias4 = (const float4*)bias;
  u16* Asl = As + w * RPW * 32;
  u16* Bsl = Bs + w * 1024;
  const int astore = (w * RPW + r) * 32 + q * 8;   // u16 idx for ASRC=1

  f32x4 acc[FM][4] = {};

  for (int kk = 0; kk < kc; kk += 32) {
    if constexpr (ASRC == 0) {
#pragma unroll
      for (int l = 0; l < NLA; ++l)
        gl2lds16(Ag + (long)l * 16 * K + kk, Asl + l * 512);
    } else {
      const float4 a0 = *(const float4*)(Atf + kk);
      const float4 a1 = *(const float4*)(Atf + kk + 4);
      const float4 b0 = bias4[((int)(k0 + kk) >> 2) + q * 2];
      const float4 b1 = bias4[((int)(k0 + kk) >> 2) + q * 2 + 1];
      *(bf16x8*)(As + astore) = pack8(f4sub(a0, b0), f4sub(a1, b1));
    }
    gl2lds16(Bg + kk, Bsl);
    gl2lds16(Bg + 16 * (long)K + kk, Bsl + 512);
    __syncthreads();
    bf16x8 af[FM], bv[4];
#pragma unroll
    for (int i = 0; i < FM; ++i)
      af[i] = *(const bf16x8*)(As + (wm * (TM/2) + i * 16 + lm) * 32 + quad * 8);
#pragma unroll
    for (int j = 0; j < 4; ++j)
      bv[j] = *(const bf16x8*)(Bs + (wn * 64 + j * 16 + lm) * 32 + quad * 8);
#pragma unroll
    for (int i = 0; i < FM; ++i)
#pragma unroll
      for (int j = 0; j < 4; ++j)
        acc[i][j] = __builtin_amdgcn_mfma_f32_16x16x32_bf16(af[i], bv[j], acc[i][j], 0, 0, 0);
    __syncthreads();
  }

  // C/D layout (m89-verified): col = lane&15, row = quad*4 + reg
  const int rbase = m0 + wm * (TM/2) + quad * 4;
  const int cbase = n0 + wn * 64 + lm;
  const long zoff = (EPI == 0) ? (long)blockIdx.z * zstride : 0;
#pragma unroll
  for (int i = 0; i < FM; ++i)
#pragma unroll
    for (int j = 0; j < 4; ++j) {
      const int col = cbase + j * 16;
#pragma unroll
      for (int rr = 0; rr < 4; ++rr) {
        const long idx = (long)(rbase + i * 16 + rr) * ldc + col;
        const float v = alpha * acc[i][j][rr];
        if constexpr (EPI == 0)      Cf[zoff + idx] = v;
        else if constexpr (EPI == 1) Cb[idx] = f2bf(v);
        else                         Cf[idx] = v + beta * bf2f(Yb[idx]);
      }
    }
}

// W[3072,768] fp32 -> WTb bf16 [768,3072]
__global__ void conv_w(const float* __restrict__ W, u16* __restrict__ WTb)
{
  const int i = blockIdx.x * 256 + threadIdx.x;   // < 2359296
  const float v = W[i];
  const int o = i / 768, c = i - o * 768;
  WTb[(long)c * 3072 + o] = f2bf(v);              // 2B scatter; 4.7MB, L2-absorbed
}

// Ef = sum_z Ep[z];  Eb = bf16(Ef).  (147456 float4 elems, 8 partials)
__global__ void red_e(const float* __restrict__ Ep, float* __restrict__ Ef,
                      u16* __restrict__ Eb)
{
  const int i4 = blockIdx.x * 256 + threadIdx.x;  // < 147456
  float4 s = make_float4(0.f, 0.f, 0.f, 0.f);
#pragma unroll
  for (int z = 0; z < 8; ++z) {
    const float4 p = ((const float4*)Ep)[(long)z * 147456 + i4];
    s.x += p.x; s.y += p.y; s.z += p.z; s.w += p.w;
  }
  ((float4*)Ef)[i4] = s;
  ushort4 o; o.x = f2bf(s.x); o.y = f2bf(s.y); o.z = f2bf(s.z); o.w = f2bf(s.w);
  ((ushort4*)Eb)[i4] = o;
}

// S''b = bf16(-45*Ef + 120*sum_z P2p[z])
__global__ void red_s(const float* __restrict__ P2p, const float* __restrict__ Ef,
                      u16* __restrict__ Spb)
{
  const int i4 = blockIdx.x * 256 + threadIdx.x;  // < 147456
  float4 s = make_float4(0.f, 0.f, 0.f, 0.f);
#pragma unroll
  for (int z = 0; z < 8; ++z) {
    const float4 p = ((const float4*)P2p)[(long)z * 147456 + i4];
    s.x += p.x; s.y += p.y; s.z += p.z; s.w += p.w;
  }
  const float4 e = ((const float4*)Ef)[i4];
  ushort4 o;
  o.x = f2bf(-45.f * e.x + 120.f * s.x);
  o.y = f2bf(-45.f * e.y + 120.f * s.y);
  o.z = f2bf(-45.f * e.z + 120.f * s.z);
  o.w = f2bf(-45.f * e.w + 120.f * s.w);
  ((ushort4*)Spb)[i4] = o;
}

extern "C" void kernel_launch(void* const* d_in, const int* in_sizes, int n_in,
                              void* d_out, int out_size, void* d_ws, size_t ws_size,
                              hipStream_t stream)
{
  const float* t    = (const float*)d_in[0];   // [8,1024,3072]
  const float* W    = (const float*)d_in[1];   // [3072,768]
  const float* bias = (const float*)d_in[2];   // [3072]
  float* out = (float*)d_out;                  // [8192,768] fp32

  char* p = (char*)d_ws;                       // 59,768,832 B used
  u16*   WTb = (u16*)(p + 0);                  //  4,718,592  bf16 W^T [768,3072]
  u16*   yb  = (u16*)(p + 4718592);            // 12,582,912  bf16 y [8192,768]
  float* Ep  = (float*)(p + 17301504);         // 18,874,368  E partials [8][768,768]
  float* P2p = (float*)(p + 36175872);         // 18,874,368  E^2 partials [8][768,768]
  float* Ef  = (float*)(p + 55050240);         //  2,359,296  E fp32
  u16*   Eb  = (u16*)(p + 57409536);           //  1,179,648  bf16 E
  u16*   Spb = (u16*)(p + 58589184);           //  1,179,648  bf16 S''

  const float lr = 0.001f;

  // 1. WTb = bf16(W^T)
  conv_w<<<9216, 256, 0, stream>>>(W, WTb);
  // 2. E partials: lr * WTb @ WTb^T, TM=64, z=8 (576 blocks, 12 iters)
  gemm<64, 0, 0><<<dim3(12, 6, 8), 256, 0, stream>>>(
      WTb, nullptr, WTb, Ep, nullptr, nullptr, lr, 0.f, 3072, 768, 384, 589824);
  // 3. Ef = sum(Ep); Eb = bf16(Ef)
  red_e<<<576, 256, 0, stream>>>(Ep, Ef, Eb);
  // 4. E^2 partials: Eb @ Eb^T (E symmetric), z=8 (576 blocks, 3 iters)
  gemm<64, 0, 0><<<dim3(12, 6, 8), 256, 0, stream>>>(
      Eb, nullptr, Eb, P2p, nullptr, nullptr, 1.f, 0.f, 768, 768, 96, 589824);
  // 5. S''b = bf16(-45E + 120E^2)
  red_s<<<576, 256, 0, stream>>>(P2p, Ef, Spb);
  // 6. GEMM1: yb = bf16((t-b) @ W); A = t fp32 staged with bias-subtract,
  //    B = WTb [768,3072]. Grid 128x6 = 768 blocks (3/CU), 96 iters.
  gemm<64, 1, 1><<<dim3(128, 6, 1), 256, 0, stream>>>(
      t, bias, WTb, nullptr, yb, nullptr, 1.f, 0.f, 3072, 768, 3072, 0);
  // 7. GEMM2: out = lr * (yb @ S''b^T) + 0.01 * yb   (S'' symmetric)
  gemm<64, 0, 2><<<dim3(128, 6, 1), 256, 0, stream>>>(
      yb, nullptr, Spb, out, nullptr, yb, lr, 0.01f, 768, 768, 768, 0);
}